// Round 7
// baseline (227.262 us; speedup 1.0000x reference)
//
#include <hip/hip_runtime.h>
#include <hip/hip_bf16.h>
#include <math.h>

#define N_PTS   2048
#define N_NODES 8192
#define N_CMP   1024
#define CAP     128     // max candidate list length per row
#define K_MIN   32
#define K_MAX   112

// Workspace: bitsT uint[N_NODES*32] @ 0 (1 MiB), qword-contiguous layout:
//   bit for (node n, column c) = dword bitsT[n*32 + (c>>5)], bit (c&31).
//   A wave covering columns cg*64..cg*64+63 needs exactly 2 dwords (1 qword).

__device__ __forceinline__ unsigned int float_to_key(float f) {
    unsigned int b = __float_as_uint(f);
    return (b & 0x80000000u) ? ~b : (b | 0x80000000u);
}
__device__ __forceinline__ float key_to_float(unsigned int k) {
    unsigned int b = (k & 0x80000000u) ? (k ^ 0x80000000u) : ~k;
    return __uint_as_float(b);
}

// ---------------- Kernel 1: bit-pack mask ----------------
// One wave per (node n, 64-col group cg): coalesced 256B load + 1 ballot.
__global__ __launch_bounds__(256) void pack_kernel(const int* __restrict__ states,
                                                   unsigned int* __restrict__ bitsT) {
    int t    = threadIdx.x;
    int lane = t & 63;
    int W    = blockIdx.x * 4 + (t >> 6);   // 0 .. 8192*16-1
    int n    = W >> 4;
    int cg   = W & 15;
    int s    = states[(size_t)n * N_CMP + cg * 64 + lane];
    unsigned long long m = __ballot(s != 0);
    if (lane == 0) {
        bitsT[n * 32 + cg * 2]     = (unsigned int)(m & 0xffffffffull);
        bitsT[n * 32 + cg * 2 + 1] = (unsigned int)(m >> 32);
    }
}

// ---------------- Kernel 2: fused select + unordered probe ----------------
// Block p: load row, bisect threshold, compact candidates (NO sort), then
// branch-free fmax scan of all candidates per column. 256 thr = 4 waves;
// wave w covers column-groups {i*4+w}.
__global__ __launch_bounds__(256) void fused_kernel(const float* __restrict__ x,
                                                    const int* __restrict__ states,
                                                    const unsigned int* __restrict__ bitsT,
                                                    float* __restrict__ out) {
    int p    = blockIdx.x;
    int t    = threadIdx.x;
    int lane = t & 63;
    int w    = t >> 6;

    const float4* row4 = reinterpret_cast<const float4*>(x + (size_t)p * N_NODES);

    // element index of key[j*4+e] is j*1024 + t*4 + e
    unsigned int key[32];
#pragma unroll
    for (int j = 0; j < 8; j++) {
        float4 v = row4[j * 256 + t];
        key[j * 4 + 0] = float_to_key(v.x);
        key[j * 4 + 1] = float_to_key(v.y);
        key[j * 4 + 2] = float_to_key(v.z);
        key[j * 4 + 3] = float_to_key(v.w);
    }

    __shared__ unsigned int s_cnt[2][4];
    __shared__ unsigned int s_red[4];
    __shared__ float        s_v[CAP];    // candidate values (UNSORTED)
    __shared__ int          s_n[CAP];    // candidate node ids
    __shared__ int          s_num;

    // ---- block max of keys (bisection upper bound) ----
    unsigned int m = 0;
#pragma unroll
    for (int i = 0; i < 32; i++) m = max(m, key[i]);
#pragma unroll
    for (int d = 1; d < 64; d <<= 1)
        m = max(m, (unsigned int)__shfl_xor((int)m, d));
    if (lane == 0) s_red[w] = m;
    __syncthreads();
    unsigned int M = max(max(s_red[0], s_red[1]), max(s_red[2], s_red[3]));

    // ---- bisection: find T with count(key >= T) in [K_MIN, K_MAX] ----
    unsigned int lo = 0, hi = M;
    for (int it = 0; it < 34; ++it) {
        if (hi - lo <= 1) break;
        unsigned int mid;
        if (it == 0) {
            mid = 0xC0200000u;                  // key(2.5f): ~51 hits on N(0,1) rows
            if (mid >= hi) mid = hi - 1;
            if (mid <= lo) mid = lo + 1;
        } else {
            mid = lo + ((hi - lo) >> 1);
        }
        int myc = 0;
#pragma unroll
        for (int i = 0; i < 32; i++)
            myc += (int)__popcll(__ballot(key[i] >= mid));
        int par = it & 1;
        if (lane == 0) s_cnt[par][w] = (unsigned int)myc;
        __syncthreads();
        int c = (int)(s_cnt[par][0] + s_cnt[par][1] + s_cnt[par][2] + s_cnt[par][3]);
        if (c >= K_MIN) {
            lo = mid;
            if (c <= K_MAX) break;
        } else {
            hi = mid;
        }
    }
    unsigned int T = lo;

    // ---- compact keys >= T into LDS (no ordering needed) ----
    if (t == 0) s_num = 0;
    __syncthreads();
#pragma unroll
    for (int i = 0; i < 32; i++) {
        if (key[i] >= T) {
            int pos = atomicAdd(&s_num, 1);
            if (pos < CAP) {
                s_v[pos] = key_to_float(key[i]);
                s_n[pos] = (i >> 2) * 1024 + (t << 2) + (i & 3);
            }
        }
    }
    __syncthreads();
    int L   = s_num;
    int len = (L > CAP) ? -1 : L;            // pathological ties -> fallback

    // ---- probe: branch-free fmax over ALL candidates ----
#pragma unroll 1
    for (int i = 0; i < 4; ++i) {
        int cg = i * 4 + w;                  // adjacent 64-col segments per i
        int c  = cg * 64 + lane;

        float res = -INFINITY;
        if (len >= 0) {
#pragma unroll 4
            for (int k = 0; k < len; ++k) {
                int n = __builtin_amdgcn_readfirstlane(s_n[k]);   // scalar addr
                unsigned int blo = bitsT[n * 32 + cg * 2];
                unsigned int bhi = bitsT[n * 32 + cg * 2 + 1];
                unsigned int ws  = (lane < 32) ? blo : bhi;
                if ((ws >> (lane & 31)) & 1u) res = fmaxf(res, s_v[k]);
            }
        }

        float r;
        if (res == -INFINITY) {
            // no candidate hit (P ~ 2^-len) or ties overflow: exact fallback
            const float* row = x + (size_t)p * N_NODES;
            float mm = -INFINITY;
            for (int n = 0; n < N_NODES; n++) {
                if (states[(size_t)n * N_CMP + c] != 0) mm = fmaxf(mm, row[n]);
            }
            r = (mm == -INFINITY) ? 0.0f : mm;   // empty column -> 0.0
        } else {
            r = res;
        }

        out[(size_t)p * N_CMP + c] = r;
    }
}

// ---------------- launch ----------------
extern "C" void kernel_launch(void* const* d_in, const int* in_sizes, int n_in,
                              void* d_out, int out_size, void* d_ws, size_t ws_size,
                              hipStream_t stream) {
    const float* x      = (const float*)d_in[0];
    const int*   states = (const int*)d_in[1];
    float*       out    = (float*)d_out;
    unsigned int* bitsT = (unsigned int*)d_ws;

    pack_kernel<<<(N_NODES * (N_CMP / 64)) / 4, 256, 0, stream>>>(states, bitsT);
    fused_kernel<<<N_PTS, 256, 0, stream>>>(x, states, bitsT, out);
}

// Round 8
// 147.813 us; speedup vs baseline: 1.5375x; 1.5375x over previous
//
#include <hip/hip_runtime.h>
#include <hip/hip_bf16.h>
#include <math.h>

#define N_PTS   2048
#define N_NODES 8192
#define N_CMP   1024
#define CAP     128     // max compacted candidates per row
#define K_MIN   32
#define K_MAX   112
#define TOPK    64      // probe uses only the top-64 (rank>=64 needed w.p. 2^-64)
#define THR     2.5f    // warm threshold: E[count]=51 for N(0,1) rows

// Workspace: bitsT uint[N_NODES*32] @ 0 (1 MiB).
// Layout: bit for (node n, column c) = dword bitsT[n*32 + (c>>5)], bit (c&31).
// Wave covering columns cg*64..+63 needs qword bitsT[n*32 + cg*2 .. +1].

__device__ __forceinline__ unsigned int float_to_key(float f) {
    unsigned int b = __float_as_uint(f);
    return (b & 0x80000000u) ? ~b : (b | 0x80000000u);
}

// ---------------- Kernel 1: bit-pack mask ----------------
__global__ __launch_bounds__(256) void pack_kernel(const int* __restrict__ states,
                                                   unsigned int* __restrict__ bitsT) {
    int t    = threadIdx.x;
    int lane = t & 63;
    int W    = blockIdx.x * 4 + (t >> 6);   // 0 .. 8192*16-1
    int n    = W >> 4;
    int cg   = W & 15;
    int s    = states[(size_t)n * N_CMP + cg * 64 + lane];
    unsigned long long m = __ballot(s != 0);
    if (lane == 0) {
        bitsT[n * 32 + cg * 2]     = (unsigned int)(m & 0xffffffffull);
        bitsT[n * 32 + cg * 2 + 1] = (unsigned int)(m >> 32);
    }
}

// ---------------- Kernel 2: autonomous per-row select + probe ----------------
// 2048 blocks x 256 thr, 8 blocks/CU => whole grid resident, 3 barriers/block.
__global__ __launch_bounds__(256, 8) void row_kernel(const float* __restrict__ x,
                                                     const unsigned int* __restrict__ bitsT,
                                                     float* __restrict__ out) {
    const int p    = blockIdx.x;
    const int t    = threadIdx.x;
    const int lane = t & 63;
    const int wv   = t >> 6;

    __shared__ float        s_val[CAP];
    __shared__ int          s_id[CAP];
    __shared__ float        s_sval[TOPK];
    __shared__ int          s_sid[TOPK];
    __shared__ unsigned int s_cnt[4];
    __shared__ unsigned int s_mask[4][16][2];   // per-wave probe bounce buffer
    __shared__ int          s_num;
    __shared__ int          s_flag;             // 1 => degenerate row, full fallback

    if (t == 0) { s_num = 0; s_flag = 0; }
    __syncthreads();

    const float4* row4 = reinterpret_cast<const float4*>(x + (size_t)p * N_NODES);

    // ---- pass 1: stream + fixed-threshold compact (no count pass) ----
#define CAND_TEST(F, IDX) do { float _f = (F); \
    if (_f >= THR) { int _pos = atomicAdd(&s_num, 1); \
        if (_pos < CAP) { s_val[_pos] = _f; s_id[_pos] = (IDX); } } } while (0)

#pragma unroll
    for (int j = 0; j < 8; j++) {
        float4 v  = row4[j * 256 + t];
        int bidx  = (j * 256 + t) * 4;
        CAND_TEST(v.x, bidx);
        CAND_TEST(v.y, bidx + 1);
        CAND_TEST(v.z, bidx + 2);
        CAND_TEST(v.w, bidx + 3);
    }
    __syncthreads();
    int L = s_num;

    // ---- rare path (~0.4% of rows): block-uniform key-space bisect ----
    if (L < K_MIN || L > CAP) {
        unsigned int lo = 0u, hi = 0xFFFFFFFFu;
        unsigned int Tk = float_to_key(THR);
        if (L > CAP) lo = Tk; else hi = Tk;       // invariant: count(lo)>=K_MIN, count(hi)<K_MIN
        for (int it = 0; it < 34 && (hi - lo) > 1u; ++it) {
            unsigned int mid = lo + ((hi - lo) >> 1);
            int myc = 0;
#pragma unroll
            for (int j = 0; j < 8; j++) {
                float4 v = row4[j * 256 + t];     // L2-hot re-read
                myc += (int)__popcll(__ballot(float_to_key(v.x) >= mid));
                myc += (int)__popcll(__ballot(float_to_key(v.y) >= mid));
                myc += (int)__popcll(__ballot(float_to_key(v.z) >= mid));
                myc += (int)__popcll(__ballot(float_to_key(v.w) >= mid));
            }
            if (lane == 0) s_cnt[wv] = (unsigned int)myc;
            __syncthreads();
            int c = (int)(s_cnt[0] + s_cnt[1] + s_cnt[2] + s_cnt[3]);
            __syncthreads();
            if (c >= K_MIN) { lo = mid; if (c <= K_MAX) break; }
            else            hi = mid;
        }
        if (t == 0) s_num = 0;
        __syncthreads();
#pragma unroll
        for (int j = 0; j < 8; j++) {
            float4 v = row4[j * 256 + t];
            int bidx = (j * 256 + t) * 4;
#define CAND_TEST2(F, IDX) do { float _f = (F); \
    if (float_to_key(_f) >= lo) { int _pos = atomicAdd(&s_num, 1); \
        if (_pos < CAP) { s_val[_pos] = _f; s_id[_pos] = (IDX); } } } while (0)
            CAND_TEST2(v.x, bidx);
            CAND_TEST2(v.y, bidx + 1);
            CAND_TEST2(v.z, bidx + 2);
            CAND_TEST2(v.w, bidx + 3);
#undef CAND_TEST2
        }
        __syncthreads();
        L = s_num;
        if (t == 0 && (L > CAP || L < 1)) s_flag = 1;   // unreachable ties window
        if (L > CAP) L = CAP;
        __syncthreads();
    }
#undef CAND_TEST

    int flag = s_flag;

    // ---- rank-sort descending, keep top-TOPK only ----
    if (!flag && t < L) {
        float mv = s_val[t];
        int   mi = s_id[t];
        int r = 0;
        for (int j = 0; j < L; ++j) {
            float vj = s_val[j];
            r += (int)((vj > mv) | ((vj == mv) & (j < t)));
        }
        if (r < TOPK) { s_sval[r] = mv; s_sid[r] = mi; }
    }
    __syncthreads();

    int Lc = (L < TOPK) ? L : TOPK;

    // ---- probe: wave wv handles cgs wv*4 .. wv*4+3 ----
    for (int i = 0; i < 4; ++i) {
        int cg = wv * 4 + i;
        int c  = cg * 64 + lane;
        int fidx = -1;

        if (!flag) {
            for (int k0 = 0; k0 < Lc; k0 += 16) {
                // lanes 0-15 gather this chunk's masks (independent 8B loads)
                int j16 = lane & 15;
                int kk  = k0 + j16;
                unsigned int m0 = 0, m1 = 0;
                if (lane < 16 && kk < Lc) {
                    const unsigned int* bp = bitsT + (size_t)s_sid[kk] * 32 + cg * 2;
                    m0 = bp[0];
                    m1 = bp[1];
                }
                if (lane < 16) { s_mask[wv][j16][0] = m0; s_mask[wv][j16][1] = m1; }
                __asm__ volatile("s_waitcnt lgkmcnt(0)" ::: "memory");
                // extract: 2-way broadcast LDS reads (free), no shuffles
                unsigned int hits = 0;
                int half = lane >> 5;
                int bit  = lane & 31;
#pragma unroll
                for (int k = 0; k < 16; k++) {
                    hits |= ((s_mask[wv][k][half] >> bit) & 1u) << k;
                }
                if (fidx < 0 && hits) fidx = k0 + (int)__builtin_ctz(hits);
                if (__all(fidx >= 0)) break;
            }
        }

        float res;
        if (fidx >= 0) {
            res = s_sval[fidx];      // first hit in descending order = masked max
        } else {
            // exact fallback (empty column, top-Lc all-miss P<=2^-32, or flagged row)
            const float* row = x + (size_t)p * N_NODES;
            float mm = -INFINITY;
            for (int n = 0; n < N_NODES; n++) {
                unsigned int w = bitsT[n * 32 + (c >> 5)];
                if ((w >> (c & 31)) & 1u) mm = fmaxf(mm, row[n]);
            }
            res = (mm == -INFINITY) ? 0.0f : mm;
        }
        out[(size_t)p * N_CMP + c] = res;
    }
}

// ---------------- launch ----------------
extern "C" void kernel_launch(void* const* d_in, const int* in_sizes, int n_in,
                              void* d_out, int out_size, void* d_ws, size_t ws_size,
                              hipStream_t stream) {
    const float* x      = (const float*)d_in[0];
    const int*   states = (const int*)d_in[1];
    float*       out    = (float*)d_out;
    unsigned int* bitsT = (unsigned int*)d_ws;

    pack_kernel<<<(N_NODES * (N_CMP / 64)) / 4, 256, 0, stream>>>(states, bitsT);
    row_kernel<<<N_PTS, 256, 0, stream>>>(x, bitsT, out);
}

// Round 9
// 129.623 us; speedup vs baseline: 1.7533x; 1.1403x over previous
//
#include <hip/hip_runtime.h>
#include <hip/hip_bf16.h>
#include <math.h>

#define N_PTS   2048
#define N_NODES 8192
#define N_CMP   1024
#define CAP     256     // max compacted candidates per row
#define K_MIN   32      // below this after pass 1 -> ladder pass
#define K_ACC   16      // accept list if >= this after ladder; else flag row
#define TOPK    64      // probe only top-64 (rank>=64 needed w.p. <= 2^-64)
#define THR1    2.5f    // E[count]=51 for N(0,1) rows
#define THR2    2.0f    // ladder rung: E[count(>=2.0)]=186

// Single dispatch. Block p owns row p completely:
//   1) 8x float4 -> regs; compact >=THR1 to LDS via atomic (no count pass)
//   2) ladder: if L<K_MIN, add [THR2,THR1) from the SAME regs (no re-read)
//   3) rank-sort desc, keep top-64
//   4) probe: wave covers 4 column-groups; chunks of 16 independent
//      coalesced states loads, first hit in desc order = masked max;
//      per-lane exact fallback on miss (P<=2^-16, ~never)
// LDS padded to ~36 KB => 4 blocks/CU => grid runs as 2 generations with
// HW backfill: fresh blocks' load bursts overlap older blocks' sort/probe.

__global__ __launch_bounds__(256, 4) void hnet_kernel(const float* __restrict__ x,
                                                      const int* __restrict__ states,
                                                      float* __restrict__ out) {
    const int p    = blockIdx.x;
    const int t    = threadIdx.x;
    const int lane = t & 63;
    const int wv   = t >> 6;

    __shared__ float s_val[CAP];
    __shared__ int   s_id[CAP];
    __shared__ float s_sval[TOPK];
    __shared__ int   s_sid[TOPK];
    __shared__ int   s_num;
    __shared__ char  s_pad[33 * 1024];   // occupancy limiter: 4 blocks/CU

    if (t == 0) s_num = 0;
    if ((int)blockIdx.y == 1) s_pad[t] = 0;   // never true; keeps pad allocated
    __syncthreads();

    const float4* row4 = reinterpret_cast<const float4*>(x + (size_t)p * N_NODES);

    // ---- load row into registers (8 independent 16B loads / thread) ----
    float4 r[8];
#pragma unroll
    for (int j = 0; j < 8; j++) r[j] = row4[j * 256 + t];

    // ---- pass 1: compact >= THR1 ----
#define PUSH(F, IDX) do { float _f = (F); int _q = atomicAdd(&s_num, 1); \
    if (_q < CAP) { s_val[_q] = _f; s_id[_q] = (IDX); } } while (0)
#pragma unroll
    for (int j = 0; j < 8; j++) {
        float4 v = r[j];
        int bidx = (j * 256 + t) * 4;
        if (v.x >= THR1) PUSH(v.x, bidx);
        if (v.y >= THR1) PUSH(v.y, bidx + 1);
        if (v.z >= THR1) PUSH(v.z, bidx + 2);
        if (v.w >= THR1) PUSH(v.w, bidx + 3);
    }
    __syncthreads();
    int L = s_num;

    // ---- ladder (block-uniform branch): add [THR2, THR1) from regs ----
    if (L < K_MIN) {
#pragma unroll
        for (int j = 0; j < 8; j++) {
            float4 v = r[j];
            int bidx = (j * 256 + t) * 4;
            if (v.x >= THR2 && v.x < THR1) PUSH(v.x, bidx);
            if (v.y >= THR2 && v.y < THR1) PUSH(v.y, bidx + 1);
            if (v.z >= THR2 && v.z < THR1) PUSH(v.z, bidx + 2);
            if (v.w >= THR2 && v.w < THR1) PUSH(v.w, bidx + 3);
        }
        __syncthreads();
        L = s_num;
    }
#undef PUSH

    // flag: list incomplete (>CAP) or too weak (<K_ACC) -> exact full fallback
    const int flag = (L > CAP) | (L < K_ACC);

    // ---- rank-sort descending, keep top-TOPK ----
    if (!flag && t < L) {
        float mv = s_val[t];
        int   mi = s_id[t];
        int rk = 0;
        for (int j = 0; j < L; ++j) {
            float vj = s_val[j];
            rk += (int)((vj > mv) | ((vj == mv) & (j < t)));
        }
        if (rk < TOPK) { s_sval[rk] = mv; s_sid[rk] = mi; }
    }
    __syncthreads();
    const int Lc = (L < TOPK) ? L : TOPK;

    // ---- probe: wave wv handles column-groups wv*4 .. wv*4+3 ----
#pragma unroll 1
    for (int i = 0; i < 4; ++i) {
        int cg = wv * 4 + i;
        int c  = cg * 64 + lane;
        int fidx = -1;

        if (!flag) {
#pragma unroll 1
            for (int k0 = 0; k0 < Lc; k0 += 16) {
                int kmax = Lc - k0;
                if (kmax > 16) kmax = 16;
                int sv[16];
#pragma unroll
                for (int j = 0; j < 16; j++) {
                    if (j < kmax) {
                        int n = __builtin_amdgcn_readfirstlane(s_sid[k0 + j]);
                        sv[j] = states[(size_t)n * N_CMP + c];   // coalesced 256B
                    }
                }
                unsigned int hits = 0;
#pragma unroll
                for (int j = 0; j < 16; j++)
                    if (j < kmax && sv[j] != 0) hits |= (1u << j);
                if (fidx < 0 && hits) fidx = k0 + (int)__builtin_ctz(hits);
                if (__all(fidx >= 0)) break;
            }
        }

        float res;
        if (fidx >= 0) {
            res = s_sval[fidx];          // first hit in desc order = masked max
        } else {
            // exact fallback: empty column / all-candidates-miss / flagged row
            const float* row = x + (size_t)p * N_NODES;
            float mm = -INFINITY;
            for (int n = 0; n < N_NODES; n++) {
                if (states[(size_t)n * N_CMP + c] != 0) mm = fmaxf(mm, row[n]);
            }
            res = (mm == -INFINITY) ? 0.0f : mm;
        }
        out[(size_t)p * N_CMP + c] = res;
    }
}

// ---------------- launch ----------------
extern "C" void kernel_launch(void* const* d_in, const int* in_sizes, int n_in,
                              void* d_out, int out_size, void* d_ws, size_t ws_size,
                              hipStream_t stream) {
    const float* x      = (const float*)d_in[0];
    const int*   states = (const int*)d_in[1];
    float*       out    = (float*)d_out;

    hnet_kernel<<<N_PTS, 256, 0, stream>>>(x, states, out);
}